// Round 7
// baseline (216.489 us; speedup 1.0000x reference)
//
#include <hip/hip_runtime.h>
#include <hip/hip_bf16.h>

typedef __attribute__((ext_vector_type(8))) short short8v;
typedef __attribute__((ext_vector_type(4))) float floatx4;
typedef __attribute__((ext_vector_type(4))) unsigned int uint4v;

union FragU { uint4v u4; unsigned int u[4]; short8v v; };

__device__ __forceinline__ unsigned int pkbf(float a, float b) {
  __hip_bfloat162 h = __float22bfloat162_rn(make_float2(a, b));
  union { __hip_bfloat162 h; unsigned int u; } c; c.h = h;
  return c.u;
}

// LDS-publishing barrier WITHOUT the vmcnt(0) drain __syncthreads implies.
// Guarantees: all this wave's LDS ops complete (lgkmcnt 0), then rendezvous.
// Global loads in flight are NOT waited — they survive the barrier (T4).
__device__ __forceinline__ void barrier_lds_only() {
  asm volatile("s_waitcnt lgkmcnt(0)" ::: "memory");
  __builtin_amdgcn_s_barrier();
}

// out[b*128+o] = bias[o]   (atomic-fallback path only)
__global__ void bias_init(const float* __restrict__ bias, float* __restrict__ out) {
  int idx = blockIdx.x * 256 + threadIdx.x;   // 32768 total
  out[idx] = bias[idx & 127];
}

// ---------------------------------------------------------------------------
// reduce_v6: out[b*128 + col] = bias[col] + sum over 128 (ig,jh) splits of
//   part[(ig*8 + jh*4 + cq)*8192 + b*32 + cl]   (col = cq*32+cl)
// grid 256 (b) x 512 threads: col = tid&127, qr = tid>>7 takes 32 m's each.
// ---------------------------------------------------------------------------
__global__ __launch_bounds__(512)
void reduce_v6(const float* __restrict__ part, const float* __restrict__ bias,
               float* __restrict__ out) {
  const int tid = threadIdx.x;
  const int col = tid & 127;
  const int qr = tid >> 7;                    // m-quarter 0..3
  const int b = blockIdx.x;

  const float* pp = part + (long)(qr * 128 + (col >> 5)) * 8192
                    + b * 32 + (col & 31);
  float s0 = 0.f, s1 = 0.f, s2 = 0.f, s3 = 0.f;
  #pragma unroll 4
  for (int n = 0; n < 32; n += 4) {
    s0 += __builtin_nontemporal_load(pp + (long)n * 32768);
    s1 += __builtin_nontemporal_load(pp + (long)(n + 1) * 32768);
    s2 += __builtin_nontemporal_load(pp + (long)(n + 2) * 32768);
    s3 += __builtin_nontemporal_load(pp + (long)(n + 3) * 32768);
  }
  float sum = (s0 + s1) + (s2 + s3);

  __shared__ float red[3][128];
  if (qr) red[qr - 1][col] = sum;
  __syncthreads();
  if (qr == 0)
    out[b * 128 + col] = sum + red[0][col] + red[1][col] + red[2][col] + bias[col];
}

// ---------------------------------------------------------------------------
// GEMM v8 = v7 structure (bf16-packed swizzled K-major LDS, convert-once
// staging, 3-deep double-tile ring, 2-period register prefetch) with ONE
// change: per-dt __syncthreads() -> barrier_lds_only().  hipcc emits
// s_waitcnt vmcnt(0) before s_barrier for __syncthreads, draining the
// dt+2/dt+4 prefetch loads every iteration (why v7 == v6).  The raw barrier
// publishes LDS (lgkmcnt 0) but lets global loads stay in flight; the
// compiler's counted vmcnt(N) before the ds_write consumption handles the
// data dependence. Numerics byte-identical to verified v6/v7.
// grid 512 = 64 i x 2 jh x 4 cq; block 256 rows x 32 cols; K-chunk 2048.
// LDS: 6 j-tiles x 4 KB + p_lds 32x257 f32 = 56.9 KB -> 2 blocks/CU.
// ---------------------------------------------------------------------------
__global__ __launch_bounds__(512, 4)
void tfn_gemm_v8(const float* __restrict__ X, const float* __restrict__ P,
                 const float* __restrict__ Dyn, const float* __restrict__ W,
                 float* __restrict__ part) {
  __shared__ unsigned int wlds[6][1024];      // 3 ring slots x 2 j-tiles
  __shared__ float p_lds[32][257];            // p[jj][b], padded

  const int tid = threadIdx.x;
  const int wv = tid >> 6, lane = tid & 63;
  const int q = lane >> 4, l16 = lane & 15;

  const int bx = blockIdx.x;
  const int ig = bx >> 3;                     // i value 0..63
  const int jh = (bx >> 2) & 1;               // j half
  const int cq = bx & 3;                      // column quarter

  // staging slot: row-pair pr (0..63) within 128-row double-tile, col chunk cc
  const int pr = tid >> 3, cc = tid & 7;
  const float* wbase = W + ((long)ig << 19) + ((long)jh << 18)
                       + (cq << 5) + (cc << 2) + (long)pr * 256;  // k-row 2*pr
  // double-tile dt at wbase + (dt<<14); second k-row at +128

  const int wtile0 = pr >> 5;                 // j-tile within double (0/1)
  const int wpr = pr & 31;                    // k-pair index within tile
  const int wcol = cc << 2;                   // base col of 4

  auto ldw = [&](int dt, floatx4& r0, floatx4& r1) {
    r0 = __builtin_nontemporal_load((const floatx4*)(wbase + ((long)dt << 14)));
    r1 = __builtin_nontemporal_load((const floatx4*)(wbase + ((long)dt << 14) + 128));
  };
  auto stage_write = [&](int slot, const floatx4& a, const floatx4& b) {
    unsigned int* tb = &wlds[(slot << 1) + wtile0][0];
    #pragma unroll
    for (int w = 0; w < 4; ++w) {
      int col = wcol + w;
      tb[((col << 5) + wpr) ^ ((col & 7) << 2)] = pkbf(a[w], b[w]);
    }
  };

  // ---- prologue: issue 2 double-tiles of loads immediately ----
  floatx4 rgA0, rgA1, rgB0, rgB1;
  ldw(0, rgA0, rgA1);
  ldw(1, rgB0, rgB1);

  // ---- stage p: 32 j-values x 256 batches ----
  #pragma unroll
  for (int it = 0; it < 16; ++it) {
    int idx = tid + (it << 9);
    int jj = idx & 31, bb = idx >> 5;
    int j = (jh << 5) + jj;
    p_lds[jj][bb] = (j < 63) ? P[bb * 63 + j] : 1.0f;
  }

  // ---- per-lane register cache: e[rt][h][t] = a * d ----
  float e[2][2][8];
  #pragma unroll
  for (int rt = 0; rt < 2; ++rt) {
    int brow = (wv << 5) + (rt << 4) + l16;
    float av = (ig < 63) ? X[brow * 63 + ig] : 1.0f;
    #pragma unroll
    for (int h = 0; h < 2; ++h) {
      int kb = (h << 5) + (q << 3);
      #pragma unroll
      for (int t = 0; t < 8; ++t) {
        int k = kb + t;
        float dv = (k < 63) ? Dyn[brow * 63 + k] : 1.0f;
        e[rt][h][t] = av * dv;
      }
    }
  }

  // ---- write dt0 -> slot0, reload A <- dt2; write dt1 -> slot1, B <- dt3 ----
  stage_write(0, rgA0, rgA1);
  ldw(2, rgA0, rgA1);
  stage_write(1, rgB0, rgB1);
  ldw(3, rgB0, rgB1);

  // ---- fragment read offsets (u32 units), swizzle folded in ----
  int roff[2][2];
  #pragma unroll
  for (int nt = 0; nt < 2; ++nt) {
    int col = (nt << 4) + l16;
    #pragma unroll
    for (int h = 0; h < 2; ++h)
      roff[nt][h] = (col << 5) + (((h << 4) + (q << 2)) ^ ((col & 7) << 2));
  }
  const int prow = (wv << 5) + l16;

  floatx4 acc[2][2];
  #pragma unroll
  for (int a = 0; a < 2; ++a)
    #pragma unroll
    for (int b = 0; b < 2; ++b) acc[a][b] = (floatx4)0.0f;

  barrier_lds_only();   // p_lds + slots 0,1 visible; prefetches stay in flight

  int csl = 0;                                // dt % 3
  for (int dt = 0; dt < 16; ++dt) {
    // 1. write double-tile dt+2 (regs 2 periods old) into the slot freed at
    //    dt-1; issue loads for dt+4.
    int wsl = csl + 2; if (wsl >= 3) wsl -= 3;
    if (dt < 14) {
      if (dt & 1) {
        stage_write(wsl, rgB0, rgB1);
        if (dt < 12) ldw(dt + 4, rgB0, rgB1);
      } else {
        stage_write(wsl, rgA0, rgA1);
        if (dt < 12) ldw(dt + 4, rgA0, rgA1);
      }
    }

    // 2. compute local j = 2dt, 2dt+1 from ring slot csl
    #pragma unroll
    for (int jj2 = 0; jj2 < 2; ++jj2) {
      int jl = (dt << 1) + jj2;
      const unsigned int* tb = &wlds[(csl << 1) + jj2][0];
      float pbv[2];
      pbv[0] = p_lds[jl][prow];
      pbv[1] = p_lds[jl][prow + 16];

      #pragma unroll
      for (int h = 0; h < 2; ++h) {
        FragU fb[2], fa[2];
        #pragma unroll
        for (int nt = 0; nt < 2; ++nt)
          fb[nt].u4 = *(const uint4v*)(tb + roff[nt][h]);
        #pragma unroll
        for (int rt = 0; rt < 2; ++rt)
          #pragma unroll
          for (int v2 = 0; v2 < 4; ++v2)
            fa[rt].u[v2] = pkbf(pbv[rt] * e[rt][h][2 * v2],
                                pbv[rt] * e[rt][h][2 * v2 + 1]);
        #pragma unroll
        for (int rt = 0; rt < 2; ++rt)
          #pragma unroll
          for (int nt = 0; nt < 2; ++nt)
            acc[rt][nt] = __builtin_amdgcn_mfma_f32_16x16x32_bf16(
                fa[rt].v, fb[nt].v, acc[rt][nt], 0, 0, 0);
      }
    }
    if (dt < 15) barrier_lds_only();
    csl += 1; if (csl == 3) csl = 0;
  }

  // ---- epilogue: store partial [256 rows, 32 cols] ----
  float* pt = part + ((long)bx << 13);        // bx * 8192
  #pragma unroll
  for (int rt = 0; rt < 2; ++rt)
    #pragma unroll
    for (int nt = 0; nt < 2; ++nt) {
      int cl = (nt << 4) + l16;
      #pragma unroll
      for (int g = 0; g < 4; ++g) {
        int row = (wv << 5) + (rt << 4) + (q << 2) + g;
        pt[row * 32 + cl] = acc[rt][nt][g];
      }
    }
}

// ---------------------------------------------------------------------------
// Fallback GEMM (verified old kernel): fp32 scalar W loads + atomics.
// Used only when no workspace is available.
// ---------------------------------------------------------------------------
__global__ __launch_bounds__(512, 2)
void tfn_gemm(const float* __restrict__ X, const float* __restrict__ P,
              const float* __restrict__ Dyn, const float* __restrict__ W,
              float* __restrict__ out) {
  __shared__ float p_lds[16][256];

  const int tid = threadIdx.x;
  const int wv = tid >> 6, lane = tid & 63;
  const int q = lane >> 4, l16 = lane & 15;
  const int r = wv & 3;
  const int cg = wv >> 2;

  const int c = blockIdx.x;
  const int i = c >> 2;
  const int j0 = (c & 3) << 4;
  const long gk0 = (long)c << 10;

  for (int idx = tid; idx < 256 * 16; idx += 512) {
    int bb = idx >> 4, jj = idx & 15;
    int j = j0 + jj;
    p_lds[jj][bb] = (j < 63) ? P[bb * 63 + j] : 1.0f;
  }

  float e[4][2][8];
  #pragma unroll
  for (int rt = 0; rt < 4; ++rt) {
    int brow = (r << 6) + (rt << 4) + l16;
    float av = (i < 63) ? X[brow * 63 + i] : 1.0f;
    #pragma unroll
    for (int h = 0; h < 2; ++h) {
      int kb = (h << 5) + (q << 3);
      #pragma unroll
      for (int t = 0; t < 8; ++t) {
        int k = kb + t;
        float dv = (k < 63) ? Dyn[brow * 63 + k] : 1.0f;
        e[rt][h][t] = av * dv;
      }
    }
  }

  floatx4 acc[4][4];
  #pragma unroll
  for (int a = 0; a < 4; ++a)
    #pragma unroll
    for (int b = 0; b < 4; ++b) acc[a][b] = (floatx4)0.0f;

  __syncthreads();

  const float* wstep = W + (gk0 + (q << 3)) * 128 + (cg << 6) + l16;

  float wA[4][8], wB[4][8];
  #pragma unroll
  for (int nt = 0; nt < 4; ++nt)
    #pragma unroll
    for (int t = 0; t < 8; ++t)
      wA[nt][t] = wstep[t * 128 + nt * 16];

  for (int jj = 0; jj < 16; ++jj) {
    float pb[4];
    #pragma unroll
    for (int rt = 0; rt < 4; ++rt)
      pb[rt] = p_lds[jj][(r << 6) + (rt << 4) + l16];

    {
      const float* wp = wstep + ((long)(2 * jj + 1) << 12);
      #pragma unroll
      for (int nt = 0; nt < 4; ++nt)
        #pragma unroll
        for (int t = 0; t < 8; ++t)
          wB[nt][t] = wp[t * 128 + nt * 16];

      union { short8v v; unsigned int u[4]; } fb[4], fa[4];
      #pragma unroll
      for (int nt = 0; nt < 4; ++nt)
        #pragma unroll
        for (int v2 = 0; v2 < 4; ++v2)
          fb[nt].u[v2] = pkbf(wA[nt][2 * v2], wA[nt][2 * v2 + 1]);
      #pragma unroll
      for (int rt = 0; rt < 4; ++rt)
        #pragma unroll
        for (int v2 = 0; v2 < 4; ++v2)
          fa[rt].u[v2] = pkbf(pb[rt] * e[rt][0][2 * v2], pb[rt] * e[rt][0][2 * v2 + 1]);
      #pragma unroll
      for (int rt = 0; rt < 4; ++rt)
        #pragma unroll
        for (int nt = 0; nt < 4; ++nt)
          acc[rt][nt] = __builtin_amdgcn_mfma_f32_16x16x32_bf16(
              fa[rt].v, fb[nt].v, acc[rt][nt], 0, 0, 0);
    }

    {
      if (jj < 15) {
        const float* wp = wstep + ((long)(2 * jj + 2) << 12);
        #pragma unroll
        for (int nt = 0; nt < 4; ++nt)
          #pragma unroll
          for (int t = 0; t < 8; ++t)
            wA[nt][t] = wp[t * 128 + nt * 16];
      }

      union { short8v v; unsigned int u[4]; } fb[4], fa[4];
      #pragma unroll
      for (int nt = 0; nt < 4; ++nt)
        #pragma unroll
        for (int v2 = 0; v2 < 4; ++v2)
          fb[nt].u[v2] = pkbf(wB[nt][2 * v2], wB[nt][2 * v2 + 1]);
      #pragma unroll
      for (int rt = 0; rt < 4; ++rt)
        #pragma unroll
        for (int v2 = 0; v2 < 4; ++v2)
          fa[rt].u[v2] = pkbf(pb[rt] * e[rt][1][2 * v2], pb[rt] * e[rt][1][2 * v2 + 1]);
      #pragma unroll
      for (int rt = 0; rt < 4; ++rt)
        #pragma unroll
        for (int nt = 0; nt < 4; ++nt)
          acc[rt][nt] = __builtin_amdgcn_mfma_f32_16x16x32_bf16(
              fa[rt].v, fb[nt].v, acc[rt][nt], 0, 0, 0);
    }
  }

  #pragma unroll
  for (int rt = 0; rt < 4; ++rt)
    #pragma unroll
    for (int nt = 0; nt < 4; ++nt) {
      int col = (cg << 6) + (nt << 4) + l16;
      #pragma unroll
      for (int g = 0; g < 4; ++g) {
        int brow = (r << 6) + (rt << 4) + (q << 2) + g;
        atomicAdd(&out[brow * 128 + col], acc[rt][nt][g]);
      }
    }
}

extern "C" void kernel_launch(void* const* d_in, const int* in_sizes, int n_in,
                              void* d_out, int out_size, void* d_ws, size_t ws_size,
                              hipStream_t stream) {
  const float* x   = (const float*)d_in[0];
  const float* p   = (const float*)d_in[1];
  const float* dyn = (const float*)d_in[2];
  const float* W   = (const float*)d_in[3];
  const float* b   = (const float*)d_in[4];
  float* out = (float*)d_out;

  const size_t part_bytes = (size_t)512 * 8192 * sizeof(float);  // 16 MiB partials

  if (d_ws != nullptr && ws_size >= part_bytes) {
    float* part = (float*)d_ws;
    tfn_gemm_v8<<<512, 512, 0, stream>>>(x, p, dyn, W, part);
    reduce_v6<<<256, 512, 0, stream>>>(part, b, out);
  } else {
    bias_init<<<128, 256, 0, stream>>>(b, out);
    tfn_gemm<<<256, 512, 0, stream>>>(x, p, dyn, W, out);
  }
}

// Round 8
// 203.883 us; speedup vs baseline: 1.0618x; 1.0618x over previous
//
#include <hip/hip_runtime.h>
#include <hip/hip_bf16.h>

typedef __attribute__((ext_vector_type(8))) short short8v;
typedef __attribute__((ext_vector_type(4))) float floatx4;
typedef __attribute__((ext_vector_type(4))) unsigned int uint4v;

union FragU { uint4v u4; unsigned int u[4]; short8v v; };

// Pack 2 f32 -> 2 bf16 (lo=a, hi=b) in ONE VALU op. hipcc lowers
// __float22bfloat162_rn to a ~10-op integer RNE sequence; gfx950 has a
// hardware packed convert (RNE per default MODE) — this was ~7x the
// kernel's VALU issue (v5 rocprof: VALUBusy 40% vs MfmaUtil 8%).
__device__ __forceinline__ unsigned int pkbf(float a, float b) {
  unsigned int r;
  asm("v_cvt_pk_bf16_f32 %0, %1, %2" : "=v"(r) : "v"(a), "v"(b));
  return r;
}

// out[b*128+o] = bias[o]   (atomic-fallback path only)
__global__ void bias_init(const float* __restrict__ bias, float* __restrict__ out) {
  int idx = blockIdx.x * 256 + threadIdx.x;   // 32768 total
  out[idx] = bias[idx & 127];
}

// ---------------------------------------------------------------------------
// reduce_v6: out[b*128 + col] = bias[col] + sum over 128 (ig,jh) splits of
//   part[(ig*8 + jh*4 + cq)*8192 + b*32 + cl]   (col = cq*32+cl)
// grid 256 (b) x 512 threads: col = tid&127, qr = tid>>7 takes 32 m's each.
// ---------------------------------------------------------------------------
__global__ __launch_bounds__(512)
void reduce_v6(const float* __restrict__ part, const float* __restrict__ bias,
               float* __restrict__ out) {
  const int tid = threadIdx.x;
  const int col = tid & 127;
  const int qr = tid >> 7;                    // m-quarter 0..3
  const int b = blockIdx.x;

  const float* pp = part + (long)(qr * 128 + (col >> 5)) * 8192
                    + b * 32 + (col & 31);
  float s0 = 0.f, s1 = 0.f, s2 = 0.f, s3 = 0.f;
  #pragma unroll 4
  for (int n = 0; n < 32; n += 4) {
    s0 += __builtin_nontemporal_load(pp + (long)n * 32768);
    s1 += __builtin_nontemporal_load(pp + (long)(n + 1) * 32768);
    s2 += __builtin_nontemporal_load(pp + (long)(n + 2) * 32768);
    s3 += __builtin_nontemporal_load(pp + (long)(n + 3) * 32768);
  }
  float sum = (s0 + s1) + (s2 + s3);

  __shared__ float red[3][128];
  if (qr) red[qr - 1][col] = sum;
  __syncthreads();
  if (qr == 0)
    out[b * 128 + col] = sum + red[0][col] + red[1][col] + red[2][col] + bias[col];
}

// ---------------------------------------------------------------------------
// GEMM v9 = v6 structure EXACTLY (best measured: 210.4 total) with pkbf as a
// single v_cvt_pk_bf16_f32. grid 512 = 64 i x 2 jh x 4 cq.
// Block: rows 256, cols 32, K-chunk 2048. Per double-tile (2 j = 128 k-rows x
// 32 cols): threads load 2 adjacent k-rows x 4 cols (2 coalesced nontemporal
// dwordx4), pack k-pairs to bf16 ONCE, write 4 u32 into K-major swizzled LDS:
//   u32 index = (col*32 + kpair) ^ ((col&7)<<2)
// Fragment read = one ds_read_b128 per (nt,h). Double-buffered double-tiles,
// one __syncthreads per dt. LDS 4x4KB + p_lds 32x257 f32 = 49.3 KB ->
// 2 blocks/CU, 16 waves/CU.
// ---------------------------------------------------------------------------
__global__ __launch_bounds__(512, 4)
void tfn_gemm_v9(const float* __restrict__ X, const float* __restrict__ P,
                 const float* __restrict__ Dyn, const float* __restrict__ W,
                 float* __restrict__ part) {
  __shared__ unsigned int wlds[4][1024];      // 4 j-tiles: 32 cols x 32 kpairs u32
  __shared__ float p_lds[32][257];            // p[jj][b], padded

  const int tid = threadIdx.x;
  const int wv = tid >> 6, lane = tid & 63;
  const int q = lane >> 4, l16 = lane & 15;

  const int bx = blockIdx.x;
  const int ig = bx >> 3;                     // i value 0..63
  const int jh = (bx >> 2) & 1;               // j half
  const int cq = bx & 3;                      // column quarter

  // staging slot: row-pair pr (0..63) within 128-row double-tile, col chunk cc
  const int pr = tid >> 3, cc = tid & 7;
  const float* wbase = W + ((long)ig << 19) + ((long)jh << 18)
                       + (cq << 5) + (cc << 2) + (long)pr * 256;  // k-row 2*pr
  // double-tile dt at wbase + (dt<<14); second row +128.

  // ---- issue DT0 loads immediately ----
  floatx4 rg0 = __builtin_nontemporal_load((const floatx4*)wbase);
  floatx4 rg1 = __builtin_nontemporal_load((const floatx4*)(wbase + 128));

  // ---- stage p: 32 j-values x 256 batches ----
  #pragma unroll
  for (int it = 0; it < 16; ++it) {
    int idx = tid + (it << 9);
    int jj = idx & 31, bb = idx >> 5;
    int j = (jh << 5) + jj;
    p_lds[jj][bb] = (j < 63) ? P[bb * 63 + j] : 1.0f;
  }

  // ---- per-lane register cache: e[rt][h][t] = a * d ----
  float e[2][2][8];
  #pragma unroll
  for (int rt = 0; rt < 2; ++rt) {
    int brow = (wv << 5) + (rt << 4) + l16;
    float av = (ig < 63) ? X[brow * 63 + ig] : 1.0f;
    #pragma unroll
    for (int h = 0; h < 2; ++h) {
      int kb = (h << 5) + (q << 3);
      #pragma unroll
      for (int t = 0; t < 8; ++t) {
        int k = kb + t;
        float dv = (k < 63) ? Dyn[brow * 63 + k] : 1.0f;
        e[rt][h][t] = av * dv;
      }
    }
  }

  // ---- staging write geometry ----
  const int wtile0 = pr >> 5;                 // tile within double (0/1)
  const int wpr = pr & 31;                    // k-pair index within tile
  const int wcol = cc << 2;                   // base col of 4

  // write DT0 into tiles {0,1}; then issue DT1 loads
  {
    unsigned int* tb = &wlds[wtile0][0];
    #pragma unroll
    for (int w = 0; w < 4; ++w) {
      int col = wcol + w;
      tb[((col << 5) + wpr) ^ ((col & 7) << 2)] = pkbf(rg0[w], rg1[w]);
    }
  }
  rg0 = __builtin_nontemporal_load((const floatx4*)(wbase + (1 << 14)));
  rg1 = __builtin_nontemporal_load((const floatx4*)(wbase + (1 << 14) + 128));

  // ---- fragment read offsets (u32 units), swizzle folded in ----
  int roff[2][2];
  #pragma unroll
  for (int nt = 0; nt < 2; ++nt) {
    int col = (nt << 4) + l16;
    #pragma unroll
    for (int h = 0; h < 2; ++h)
      roff[nt][h] = (col << 5) + (((h << 4) + (q << 2)) ^ ((col & 7) << 2));
  }
  const int prow = (wv << 5) + l16;

  floatx4 acc[2][2];
  #pragma unroll
  for (int a = 0; a < 2; ++a)
    #pragma unroll
    for (int b = 0; b < 2; ++b) acc[a][b] = (floatx4)0.0f;

  __syncthreads();   // p_lds + DT0 tiles visible

  for (int dt = 0; dt < 16; ++dt) {
    // 1. write next double-tile (regs loaded last iter); issue loads for dt+2
    if (dt < 15) {
      unsigned int* tb = &wlds[(((dt + 1) & 1) << 1) + wtile0][0];
      #pragma unroll
      for (int w = 0; w < 4; ++w) {
        int col = wcol + w;
        tb[((col << 5) + wpr) ^ ((col & 7) << 2)] = pkbf(rg0[w], rg1[w]);
      }
      if (dt < 14) {
        rg0 = __builtin_nontemporal_load((const floatx4*)(wbase + ((long)(dt + 2) << 14)));
        rg1 = __builtin_nontemporal_load((const floatx4*)(wbase + ((long)(dt + 2) << 14) + 128));
      }
    }

    // 2. compute local j = 2dt, 2dt+1 from tiles (dt&1)*2 + {0,1}
    #pragma unroll
    for (int jj2 = 0; jj2 < 2; ++jj2) {
      int jl = (dt << 1) + jj2;
      const unsigned int* tb = &wlds[((dt & 1) << 1) + jj2][0];
      float pbv[2];
      pbv[0] = p_lds[jl][prow];
      pbv[1] = p_lds[jl][prow + 16];

      #pragma unroll
      for (int h = 0; h < 2; ++h) {
        FragU fb[2], fa[2];
        #pragma unroll
        for (int nt = 0; nt < 2; ++nt)
          fb[nt].u4 = *(const uint4v*)(tb + roff[nt][h]);
        #pragma unroll
        for (int rt = 0; rt < 2; ++rt)
          #pragma unroll
          for (int v2 = 0; v2 < 4; ++v2)
            fa[rt].u[v2] = pkbf(pbv[rt] * e[rt][h][2 * v2],
                                pbv[rt] * e[rt][h][2 * v2 + 1]);
        #pragma unroll
        for (int rt = 0; rt < 2; ++rt)
          #pragma unroll
          for (int nt = 0; nt < 2; ++nt)
            acc[rt][nt] = __builtin_amdgcn_mfma_f32_16x16x32_bf16(
                fa[rt].v, fb[nt].v, acc[rt][nt], 0, 0, 0);
      }
    }
    if (dt < 15) __syncthreads();
  }

  // ---- epilogue: store partial [256 rows, 32 cols] ----
  float* pt = part + ((long)bx << 13);        // bx * 8192
  #pragma unroll
  for (int rt = 0; rt < 2; ++rt)
    #pragma unroll
    for (int nt = 0; nt < 2; ++nt) {
      int cl = (nt << 4) + l16;
      #pragma unroll
      for (int g = 0; g < 4; ++g) {
        int row = (wv << 5) + (rt << 4) + (q << 2) + g;
        pt[row * 32 + cl] = acc[rt][nt][g];
      }
    }
}

// ---------------------------------------------------------------------------
// Fallback GEMM (verified old kernel): fp32 scalar W loads + atomics.
// Used only when no workspace is available.
// ---------------------------------------------------------------------------
__global__ __launch_bounds__(512, 2)
void tfn_gemm(const float* __restrict__ X, const float* __restrict__ P,
              const float* __restrict__ Dyn, const float* __restrict__ W,
              float* __restrict__ out) {
  __shared__ float p_lds[16][256];

  const int tid = threadIdx.x;
  const int wv = tid >> 6, lane = tid & 63;
  const int q = lane >> 4, l16 = lane & 15;
  const int r = wv & 3;
  const int cg = wv >> 2;

  const int c = blockIdx.x;
  const int i = c >> 2;
  const int j0 = (c & 3) << 4;
  const long gk0 = (long)c << 10;

  for (int idx = tid; idx < 256 * 16; idx += 512) {
    int bb = idx >> 4, jj = idx & 15;
    int j = j0 + jj;
    p_lds[jj][bb] = (j < 63) ? P[bb * 63 + j] : 1.0f;
  }

  float e[4][2][8];
  #pragma unroll
  for (int rt = 0; rt < 4; ++rt) {
    int brow = (r << 6) + (rt << 4) + l16;
    float av = (i < 63) ? X[brow * 63 + i] : 1.0f;
    #pragma unroll
    for (int h = 0; h < 2; ++h) {
      int kb = (h << 5) + (q << 3);
      #pragma unroll
      for (int t = 0; t < 8; ++t) {
        int k = kb + t;
        float dv = (k < 63) ? Dyn[brow * 63 + k] : 1.0f;
        e[rt][h][t] = av * dv;
      }
    }
  }

  floatx4 acc[4][4];
  #pragma unroll
  for (int a = 0; a < 4; ++a)
    #pragma unroll
    for (int b = 0; b < 4; ++b) acc[a][b] = (floatx4)0.0f;

  __syncthreads();

  const float* wstep = W + (gk0 + (q << 3)) * 128 + (cg << 6) + l16;

  float wA[4][8], wB[4][8];
  #pragma unroll
  for (int nt = 0; nt < 4; ++nt)
    #pragma unroll
    for (int t = 0; t < 8; ++t)
      wA[nt][t] = wstep[t * 128 + nt * 16];

  for (int jj = 0; jj < 16; ++jj) {
    float pb[4];
    #pragma unroll
    for (int rt = 0; rt < 4; ++rt)
      pb[rt] = p_lds[jj][(r << 6) + (rt << 4) + l16];

    {
      const float* wp = wstep + ((long)(2 * jj + 1) << 12);
      #pragma unroll
      for (int nt = 0; nt < 4; ++nt)
        #pragma unroll
        for (int t = 0; t < 8; ++t)
          wB[nt][t] = wp[t * 128 + nt * 16];

      union { short8v v; unsigned int u[4]; } fb[4], fa[4];
      #pragma unroll
      for (int nt = 0; nt < 4; ++nt)
        #pragma unroll
        for (int v2 = 0; v2 < 4; ++v2)
          fb[nt].u[v2] = pkbf(wA[nt][2 * v2], wA[nt][2 * v2 + 1]);
      #pragma unroll
      for (int rt = 0; rt < 4; ++rt)
        #pragma unroll
        for (int v2 = 0; v2 < 4; ++v2)
          fa[rt].u[v2] = pkbf(pb[rt] * e[rt][0][2 * v2], pb[rt] * e[rt][0][2 * v2 + 1]);
      #pragma unroll
      for (int rt = 0; rt < 4; ++rt)
        #pragma unroll
        for (int nt = 0; nt < 4; ++nt)
          acc[rt][nt] = __builtin_amdgcn_mfma_f32_16x16x32_bf16(
              fa[rt].v, fb[nt].v, acc[rt][nt], 0, 0, 0);
    }

    {
      if (jj < 15) {
        const float* wp = wstep + ((long)(2 * jj + 2) << 12);
        #pragma unroll
        for (int nt = 0; nt < 4; ++nt)
          #pragma unroll
          for (int t = 0; t < 8; ++t)
            wA[nt][t] = wp[t * 128 + nt * 16];
      }

      union { short8v v; unsigned int u[4]; } fb[4], fa[4];
      #pragma unroll
      for (int nt = 0; nt < 4; ++nt)
        #pragma unroll
        for (int v2 = 0; v2 < 4; ++v2)
          fb[nt].u[v2] = pkbf(wB[nt][2 * v2], wB[nt][2 * v2 + 1]);
      #pragma unroll
      for (int rt = 0; rt < 4; ++rt)
        #pragma unroll
        for (int v2 = 0; v2 < 4; ++v2)
          fa[rt].u[v2] = pkbf(pb[rt] * e[rt][1][2 * v2], pb[rt] * e[rt][1][2 * v2 + 1]);
      #pragma unroll
      for (int rt = 0; rt < 4; ++rt)
        #pragma unroll
        for (int nt = 0; nt < 4; ++nt)
          acc[rt][nt] = __builtin_amdgcn_mfma_f32_16x16x32_bf16(
              fa[rt].v, fb[nt].v, acc[rt][nt], 0, 0, 0);
    }
  }

  #pragma unroll
  for (int rt = 0; rt < 4; ++rt)
    #pragma unroll
    for (int nt = 0; nt < 4; ++nt) {
      int col = (cg << 6) + (nt << 4) + l16;
      #pragma unroll
      for (int g = 0; g < 4; ++g) {
        int brow = (r << 6) + (rt << 4) + (q << 2) + g;
        atomicAdd(&out[brow * 128 + col], acc[rt][nt][g]);
      }
    }
}

extern "C" void kernel_launch(void* const* d_in, const int* in_sizes, int n_in,
                              void* d_out, int out_size, void* d_ws, size_t ws_size,
                              hipStream_t stream) {
  const float* x   = (const float*)d_in[0];
  const float* p   = (const float*)d_in[1];
  const float* dyn = (const float*)d_in[2];
  const float* W   = (const float*)d_in[3];
  const float* b   = (const float*)d_in[4];
  float* out = (float*)d_out;

  const size_t part_bytes = (size_t)512 * 8192 * sizeof(float);  // 16 MiB partials

  if (d_ws != nullptr && ws_size >= part_bytes) {
    float* part = (float*)d_ws;
    tfn_gemm_v9<<<512, 512, 0, stream>>>(x, p, dyn, W, part);
    reduce_v6<<<256, 512, 0, stream>>>(part, b, out);
  } else {
    bias_init<<<128, 256, 0, stream>>>(b, out);
    tfn_gemm<<<256, 512, 0, stream>>>(x, p, dyn, W, out);
  }
}